// Round 4
// baseline (714.995 us; speedup 1.0000x reference)
//
#include <hip/hip_runtime.h>
#include <hip/hip_bf16.h>
#include <stdint.h>

// ---- problem constants ----
#define TT        8192          // tokens = B*S
#define HD        1024          // hidden
#define FD        2048          // intermediate
#define NE        8             // routed experts
#define CAPE      2048          // capacity per expert
#define NASS      (TT*2)        // assignments (top-2)
#define ROWS_RT   (NE*CAPE)     // 16384 routed slot rows
#define ROWS_ALL  (ROWS_RT+TT)  // 24576

using bf16x8 = __attribute__((ext_vector_type(8))) short;
using f32x4  = __attribute__((ext_vector_type(4))) float;
using f32x16 = __attribute__((ext_vector_type(16))) float;

__device__ __forceinline__ float bf2f(unsigned short h){ return __uint_as_float(((unsigned)h)<<16); }
__device__ __forceinline__ unsigned short f2bf(float f){
  unsigned u = __float_as_uint(f);
  return (unsigned short)((u + 0x7fffu + ((u>>16)&1u)) >> 16);   // RNE
}
__device__ __forceinline__ void gl_lds16(const void* g, void* l){
  __builtin_amdgcn_global_load_lds((const __attribute__((address_space(1))) unsigned*)g,
                                   (__attribute__((address_space(3))) unsigned*)l, 16, 0, 0);
}

// ===================== 1. RMSNorm + gate (softmax/top-2) =====================
__global__ void k_rms_gate(const float* __restrict__ x, const float* __restrict__ rmsw,
                           const float* __restrict__ gw,
                           unsigned short* __restrict__ xn,
                           int* __restrict__ tkidx, float* __restrict__ tkw)
{
  __shared__ __align__(16) float sh[HD];
  __shared__ float red[4];
  __shared__ float lg[NE];
  const int t = blockIdx.x, tid = threadIdx.x;
  float4 v = ((const float4*)(x + (size_t)t*HD))[tid];
  float ss = v.x*v.x + v.y*v.y + v.z*v.z + v.w*v.w;
  #pragma unroll
  for (int s=32; s; s>>=1) ss += __shfl_down(ss, s);
  if ((tid&63)==0) red[tid>>6] = ss;
  __syncthreads();
  float inv = 1.0f / sqrtf((red[0]+red[1]+red[2]+red[3]) * (1.0f/HD) + 1e-6f);
  float4 w4 = ((const float4*)rmsw)[tid];
  float n0 = v.x*inv*w4.x, n1 = v.y*inv*w4.y, n2 = v.z*inv*w4.z, n3 = v.w*inv*w4.w;
  sh[tid*4+0]=n0; sh[tid*4+1]=n1; sh[tid*4+2]=n2; sh[tid*4+3]=n3;
  ushort4 q; q.x=f2bf(n0); q.y=f2bf(n1); q.z=f2bf(n2); q.w=f2bf(n3);
  ((ushort4*)(xn + (size_t)t*HD))[tid] = q;
  __syncthreads();
  const int e = tid>>5, l = tid&31;
  const float* g = gw + e*HD;
  float acc = 0.f;
  #pragma unroll 4
  for (int c=l; c<HD; c+=32) acc += sh[c]*g[c];
  #pragma unroll
  for (int s=16; s; s>>=1) acc += __shfl_xor(acc, s);
  if (l==0) lg[e] = acc;
  __syncthreads();
  if (tid==0){
    float mx = lg[0];
    #pragma unroll
    for (int i=1;i<NE;i++) mx = fmaxf(mx, lg[i]);
    float p[NE]; float Z=0.f;
    #pragma unroll
    for (int i=0;i<NE;i++){ p[i]=expf(lg[i]-mx); Z+=p[i]; }
    int i0=0;
    #pragma unroll
    for (int i=1;i<NE;i++) if (p[i] > p[i0]) i0=i;
    int i1=(i0==0)?1:0;
    #pragma unroll
    for (int i=0;i<NE;i++) if (i!=i0 && p[i] > p[i1]) i1=i;
    float s0=p[i0]/Z, s1=p[i1]/Z;
    float d = s0+s1+1e-20f;
    tkidx[2*t]=i0; tkidx[2*t+1]=i1;
    tkw[2*t]=s0/d; tkw[2*t+1]=s1/d;
  }
}

// ===================== 2. stable capacity-limited dispatch =====================
__global__ void k_dispatch(const int* __restrict__ tkidx,
                           int* __restrict__ tok, int* __restrict__ smap)
{
  const int e = threadIdx.x>>6, lane = threadIdx.x&63;
  int base = 0;
  for (int c=0; c<NASS; c+=256){
    int v0=tkidx[c+lane], v1=tkidx[c+64+lane], v2=tkidx[c+128+lane], v3=tkidx[c+192+lane];
    #pragma unroll
    for (int u=0; u<4; ++u){
      int v = (u==0)?v0:(u==1)?v1:(u==2)?v2:v3;
      int a0 = c + u*64;
      unsigned long long m = __ballot(v==e);
      if (v==e){
        int slot = base + __popcll(m & ((1ull<<lane)-1ull));
        int a = a0 + lane;
        smap[a] = (slot < CAPE) ? (e*CAPE + slot) : -1;
        if (slot < CAPE) tok[e*CAPE + slot] = a>>1;
      }
      base += __popcll(m);
    }
  }
  for (int s = base + lane; s < CAPE; s += 64) tok[e*CAPE + s] = 0;
}

// ===================== 3. fp32 -> bf16 weight conversion =====================
__global__ void k_cvt3(const float* __restrict__ a, const float* __restrict__ b,
                       const float* __restrict__ c,
                       unsigned short* __restrict__ da, unsigned short* __restrict__ db,
                       unsigned short* __restrict__ dc, int n4)
{
  int i = blockIdx.x*blockDim.x + threadIdx.x;
  const int st = gridDim.x*blockDim.x;
  for (; i<n4; i+=st){
    float4 v; ushort4 o;
    v = ((const float4*)a)[i]; o.x=f2bf(v.x); o.y=f2bf(v.y); o.z=f2bf(v.z); o.w=f2bf(v.w); ((ushort4*)da)[i]=o;
    v = ((const float4*)b)[i]; o.x=f2bf(v.x); o.y=f2bf(v.y); o.z=f2bf(v.z); o.w=f2bf(v.w); ((ushort4*)db)[i]=o;
    v = ((const float4*)c)[i]; o.x=f2bf(v.x); o.y=f2bf(v.y); o.z=f2bf(v.z); o.w=f2bf(v.w); ((ushort4*)dc)[i]=o;
  }
}

// =====================================================================
// 256x256 GEMM, mfma 32x32x16, per-k-slice phases (full A x B reuse).
// LDS 128 KiB: A slots @0/@32KB, B slots @64KB/@96KB (bytes). Per slot:
// 4 ks-regions of [256 rows][16 ushorts] (8 KiB each). Stage = 2 ks-regions
// (2 gl_lds/thread, 16 KiB). Phases per K-tile = 4 (ks 0..3); each phase:
// 6 ds_read_b128 (4 A-frags + 2 B-frags) + 8 MFMA(32x32x16).
// Stage schedule (iter t): ph1: A-ks23(t+1), ph2: B-ks23(t+1),
//                          ph3: A-ks01(t+2), ph4: B-ks01(t+2)
// Gates: vmcnt(8) end of ph2 (covers ph3/ph4 reads = stages t-1) and end of
// ph4 (covers ph1/ph2 reads of t+1 = stages t-1). FIFO: 2 loads/stage, 4
// newer stage-ops at each gate point -> 8. Region overwrite safety: each
// stage's target region was last read >=1 barrier before the stage issues.
// =====================================================================

#define PHASE32(KS, STG, GATE) do{                                         \
    const unsigned short* As_ = &lds[(t&1)*16384];                         \
    const unsigned short* Bs_ = &lds[32768 + (t&1)*16384];                 \
    bf16x8 af[4]; bf16x8 bq[2];                                            \
    _Pragma("unroll") for (int mi=0;mi<4;++mi)                             \
      af[mi] = *(const bf16x8*)&As_[KS*4096 + (wr*128 + mi*32 + l31)*16 + h8*8]; \
    _Pragma("unroll") for (int nq=0;nq<2;++nq)                             \
      bq[nq] = *(const bf16x8*)&Bs_[KS*4096 + (wc*64 + nq*32 + l31)*16 + h8*8]; \
    STG;                                                                   \
    __builtin_amdgcn_s_barrier();                                          \
    asm volatile("s_waitcnt lgkmcnt(0)" ::: "memory");                     \
    __builtin_amdgcn_sched_barrier(0);                                     \
    __builtin_amdgcn_s_setprio(1);                                         \
    _Pragma("unroll") for (int mi=0;mi<4;++mi)                             \
      _Pragma("unroll") for (int nq=0;nq<2;++nq)                           \
        acc[mi][nq] = __builtin_amdgcn_mfma_f32_32x32x16_bf16(             \
            af[mi], bq[nq], acc[mi][nq], 0,0,0);                           \
    __builtin_amdgcn_s_setprio(0);                                         \
    __builtin_amdgcn_sched_barrier(0);                                     \
    GATE;                                                                  \
    __builtin_amdgcn_s_barrier();                                          \
    __builtin_amdgcn_sched_barrier(0);                                     \
  }while(0)

#define GATE8 asm volatile("s_waitcnt vmcnt(8)" ::: "memory")
#define NOGATE ((void)0)

// ===================== 4. gate+up fused 256^2 GEMM =====================
// grid flat 1536 blocks (16 f-tiles x 96 M-tiles), XCD-swizzled: each XCD
// owns 12 whole M-panels. B virtual rows interleave Wg/Wu per 32-row group:
// acc[mi][0]=g, acc[mi][1]=u for the SAME f per lane.
#define GU_NT 16
__global__ __launch_bounds__(512) void k_gateup256(
    const unsigned short* __restrict__ xn,
    const unsigned short* __restrict__ wgb, const unsigned short* __restrict__ wub,
    const unsigned short* __restrict__ swgb, const unsigned short* __restrict__ swub,
    const int* __restrict__ tok, unsigned short* __restrict__ Aws)
{
  __shared__ __align__(16) unsigned short lds[65536];   // 128 KiB
  const int tid = threadIdx.x;
  // bijective XCD swizzle (nwg=1536, q=192): 12 M-panels per XCD
  const int bid = blockIdx.x;
  const int wg  = (bid & 7)*192 + (bid >> 3);
  const int ft  = wg & 15, my = wg >> 4;
  const bool routed = my < 64;
  const int rowbase = my*256;
  const int shbase  = (my-64)*256;
  const unsigned short* pg = routed ? (wgb + (size_t)(my>>3)*FD*HD) : swgb;
  const unsigned short* pu = routed ? (wub + (size_t)(my>>3)*FD*HD) : swub;

  // stage sources: thread -> (srow = tid>>1, hh = tid&1)
  const int srow = tid>>1, hh = tid&1;
  const int agrow = routed ? tok[rowbase + srow] : (shbase + srow);
  const unsigned short* aRow = xn + (size_t)agrow*HD + hh*8;
  const unsigned short* bRow = ((srow&32)? pu : pg)
      + (size_t)(ft*128 + ((srow>>6)<<5) + (srow&31))*HD + hh*8;

  auto S_A = [&](int j01, int tt){
    int slot = tt&1, kk = (tt & (GU_NT-1))*64;
    #pragma unroll
    for (int j=0;j<2;j++){
      int ks = j01*2 + j;
      gl_lds16(aRow + kk + ks*16, (char*)lds + slot*32768 + ks*8192 + tid*16);
    }
  };
  auto S_B = [&](int j01, int tt){
    int slot = tt&1, kk = (tt & (GU_NT-1))*64;
    #pragma unroll
    for (int j=0;j<2;j++){
      int ks = j01*2 + j;
      gl_lds16(bRow + kk + ks*16, (char*)lds + 65536 + slot*32768 + ks*8192 + tid*16);
    }
  };

  const int wv = tid>>6, lane = tid&63;
  const int wr = wv>>2, wc = wv&3;
  const int l31 = lane&31, h8 = lane>>5;

  f32x16 acc[4][2] = {};

  // prologue: A01(0) B01(0) A23(0) B23(0) A01(1) B01(1) -> gate 8 -> barrier
  S_A(0,0); S_B(0,0); S_A(1,0); S_B(1,0); S_A(0,1); S_B(0,1);
  GATE8;
  __builtin_amdgcn_s_barrier();
  __builtin_amdgcn_sched_barrier(0);

  for (int t=0; t<GU_NT; ++t){
    PHASE32(0, S_A(1,t+1), NOGATE);
    PHASE32(1, S_B(1,t+1), GATE8);
    PHASE32(2, S_A(0,t+2), NOGATE);
    PHASE32(3, S_B(0,t+2), GATE8);
  }

  // epilogue: act = silu(g)*u ; C layout (32x32): col=l31, row=(r&3)+8*(r>>2)+4*h8
  asm volatile("s_waitcnt vmcnt(0) lgkmcnt(0)" ::: "memory");
  __builtin_amdgcn_s_barrier();
  __builtin_amdgcn_sched_barrier(0);
  #pragma unroll
  for (int mi=0;mi<4;++mi){
    f32x16 g = acc[mi][0], u = acc[mi][1];
    #pragma unroll
    for (int r=0;r<16;++r){
      float gg = g[r], uu = u[r];
      float act = (gg / (1.0f + expf(-gg))) * uu;
      int row = wr*128 + mi*32 + (r&3) + 8*(r>>2) + 4*h8;
      int fl  = wc*32 + l31;
      lds[row*128 + fl] = f2bf(act);
    }
  }
  __syncthreads();
  const size_t gb = (size_t)(routed ? rowbase : (ROWS_RT + shbase)) * FD + (size_t)ft*128;
  #pragma unroll
  for (int i=0;i<8;i++){
    int chunk = i*512 + tid;
    int row = chunk>>4, ccs = chunk&15;
    *(uint4*)&Aws[gb + (size_t)row*FD + ccs*8] = *(const uint4*)&lds[chunk*8];
  }
}

// ===================== 5. down-proj 256^2 GEMM =====================
// grid flat 384 blocks (4 n-tiles x 96 M-tiles), XCD-swizzled (q=48).
#define DN_NT 32
__global__ __launch_bounds__(512) void k_down256(
    const unsigned short* __restrict__ Aws,
    const unsigned short* __restrict__ wdb, const unsigned short* __restrict__ swdb,
    unsigned short* __restrict__ Yws)
{
  __shared__ __align__(16) unsigned short lds[65536];
  const int tid = threadIdx.x;
  const int bid = blockIdx.x;
  const int wg  = (bid & 7)*48 + (bid >> 3);
  const int nt  = wg & 3, my = wg >> 2;
  const bool routed = my < 64;
  const int rowbase = my*256;
  const unsigned short* wsel = routed ? (wdb + (size_t)(my>>3)*HD*FD) : swdb;

  const int srow = tid>>1, hh = tid&1;
  const unsigned short* aRow = Aws + (size_t)(rowbase + srow)*FD + hh*8;
  const unsigned short* bRow = wsel + (size_t)(nt*256 + srow)*FD + hh*8;

  auto S_A = [&](int j01, int tt){
    int slot = tt&1, kk = (tt & (DN_NT-1))*64;
    #pragma unroll
    for (int j=0;j<2;j++){
      int ks = j01*2 + j;
      gl_lds16(aRow + kk + ks*16, (char*)lds + slot*32768 + ks*8192 + tid*16);
    }
  };
  auto S_B = [&](int j01, int tt){
    int slot = tt&1, kk = (tt & (DN_NT-1))*64;
    #pragma unroll
    for (int j=0;j<2;j++){
      int ks = j01*2 + j;
      gl_lds16(bRow + kk + ks*16, (char*)lds + 65536 + slot*32768 + ks*8192 + tid*16);
    }
  };

  const int wv = tid>>6, lane = tid&63;
  const int wr = wv>>2, wc = wv&3;
  const int l31 = lane&31, h8 = lane>>5;

  f32x16 acc[4][2] = {};

  S_A(0,0); S_B(0,0); S_A(1,0); S_B(1,0); S_A(0,1); S_B(0,1);
  GATE8;
  __builtin_amdgcn_s_barrier();
  __builtin_amdgcn_sched_barrier(0);

  for (int t=0; t<DN_NT; ++t){
    PHASE32(0, S_A(1,t+1), NOGATE);
    PHASE32(1, S_B(1,t+1), GATE8);
    PHASE32(2, S_A(0,t+2), NOGATE);
    PHASE32(3, S_B(0,t+2), GATE8);
  }

  asm volatile("s_waitcnt vmcnt(0) lgkmcnt(0)" ::: "memory");
  __builtin_amdgcn_s_barrier();
  __builtin_amdgcn_sched_barrier(0);
  #pragma unroll
  for (int mi=0;mi<4;++mi)
    #pragma unroll
    for (int nq=0;nq<2;++nq)
      #pragma unroll
      for (int r=0;r<16;++r){
        int row = wr*128 + mi*32 + (r&3) + 8*(r>>2) + 4*h8;
        int col = wc*64 + nq*32 + l31;
        lds[row*256 + col] = f2bf(acc[mi][nq][r]);
      }
  __syncthreads();
  const size_t gb = (size_t)rowbase*HD + (size_t)nt*256;
  #pragma unroll
  for (int i=0;i<16;i++){
    int chunk = i*512 + tid;
    int row = chunk>>5, ccs = chunk&31;
    *(uint4*)&Yws[gb + (size_t)row*HD + ccs*8] = *(const uint4*)&lds[chunk*8];
  }
}

// ===================== 6. combine =====================
__global__ void k_combine(const unsigned short* __restrict__ Yws,
                          const int* __restrict__ smap, const float* __restrict__ tkw,
                          float* __restrict__ out)
{
  const int t = blockIdx.x, tid = threadIdx.x;
  const int s0 = smap[2*t], s1 = smap[2*t+1];
  const float w0 = tkw[2*t], w1 = tkw[2*t+1];
  ushort4 ys = ((const ushort4*)(Yws + (size_t)(ROWS_RT + t)*HD))[tid];
  float r0 = bf2f(ys.x), r1 = bf2f(ys.y), r2 = bf2f(ys.z), r3 = bf2f(ys.w);
  if (s0 >= 0){
    ushort4 a = ((const ushort4*)(Yws + (size_t)s0*HD))[tid];
    r0 += w0*bf2f(a.x); r1 += w0*bf2f(a.y); r2 += w0*bf2f(a.z); r3 += w0*bf2f(a.w);
  }
  if (s1 >= 0){
    ushort4 a = ((const ushort4*)(Yws + (size_t)s1*HD))[tid];
    r0 += w1*bf2f(a.x); r1 += w1*bf2f(a.y); r2 += w1*bf2f(a.z); r3 += w1*bf2f(a.w);
  }
  float4 o; o.x=r0; o.y=r1; o.z=r2; o.w=r3;
  ((float4*)(out + (size_t)t*HD))[tid] = o;
  if (t==0 && tid==0) out[(size_t)TT*HD] = 0.0f;
}

// ===================== launch =====================
// Workspace (aliased, peak ~220.3 MiB): region A [0,48M): xn+wgb then Yws;
// [48,80) wub; [80,112) wdb; [112,124) shared weights; [124,220) Aws; tables after.
extern "C" void kernel_launch(void* const* d_in, const int* in_sizes, int n_in,
                              void* d_out, int out_size, void* d_ws, size_t ws_size,
                              hipStream_t stream)
{
  const float* x    = (const float*)d_in[0];
  const float* rmsw = (const float*)d_in[1];
  const float* gw   = (const float*)d_in[2];
  const float* wg   = (const float*)d_in[3];
  const float* wu   = (const float*)d_in[4];
  const float* wd   = (const float*)d_in[5];
  const float* swg  = (const float*)d_in[6];
  const float* swu  = (const float*)d_in[7];
  const float* swd  = (const float*)d_in[8];
  float* out = (float*)d_out;

  char* ws = (char*)d_ws;
  unsigned short* xn   = (unsigned short*)(ws + 0);            // 16 MiB (dead after gateup)
  unsigned short* wgb  = (unsigned short*)(ws + 16777216);     // 32 MiB (dead after gateup)
  unsigned short* Yws  = (unsigned short*)(ws + 0);            // 48 MiB ALIASES xn+wgb
  unsigned short* wub  = (unsigned short*)(ws + 50331648);     // 32 MiB
  unsigned short* wdb  = (unsigned short*)(ws + 83886080);     // 32 MiB
  unsigned short* swgb = (unsigned short*)(ws + 117440512);    // 4 MiB
  unsigned short* swub = (unsigned short*)(ws + 121634816);    // 4 MiB
  unsigned short* swdb = (unsigned short*)(ws + 125829120);    // 4 MiB
  unsigned short* Aws  = (unsigned short*)(ws + 130023424);    // 96 MiB [24576][2048]
  int*   tkidx = (int*)  (ws + 230686720);
  float* tkw   = (float*)(ws + 230752256);
  int*   tok   = (int*)  (ws + 230817792);
  int*   smap  = (int*)  (ws + 230883328);

  k_rms_gate<<<dim3(TT), dim3(256), 0, stream>>>(x, rmsw, gw, xn, tkidx, tkw);
  k_dispatch<<<dim3(1), dim3(512), 0, stream>>>(tkidx, tok, smap);
  k_cvt3<<<dim3(1024), dim3(256), 0, stream>>>(wg, wu, wd, wgb, wub, wdb, (NE*FD*HD)/4);
  k_cvt3<<<dim3(256), dim3(256), 0, stream>>>(swg, swu, swd, swgb, swub, swdb, (FD*HD)/4);
  k_gateup256<<<dim3(1536), dim3(512), 0, stream>>>(xn, wgb, wub, swgb, swub, tok, Aws);
  k_down256<<<dim3(384), dim3(512), 0, stream>>>(Aws, wdb, swdb, Yws);
  k_combine<<<dim3(TT), dim3(256), 0, stream>>>(Yws, smap, tkw, out);
}